// Round 17
// baseline (75.678 us; speedup 1.0000x reference)
//
#include <hip/hip_runtime.h>
#include <hip/hip_bf16.h>

#define NTAGS 64
#define START_TAG 1
#define END_TAG 63
#define LN2F 0.69314718055994530942f
#define NSEG 64
#define SEGL 8
#define EP 35  // padded dword stride per 16-row in E-staging LDS

typedef float v4f __attribute__((ext_vector_type(4)));
typedef short s16x8 __attribute__((ext_vector_type(8)));

static __device__ __forceinline__ unsigned short f2bfu(float x) {
    union { __hip_bfloat16 h; unsigned short s; } u;
    u.h = __float2bfloat16(x);
    return u.s;
}
static __device__ __forceinline__ unsigned int packbf(float lo, float hi) {
    return (unsigned int)f2bfu(lo) | ((unsigned int)f2bfu(hi) << 16);
}
static __device__ __forceinline__ float bf_lo(unsigned int u) {
    return __uint_as_float(u << 16);
}
static __device__ __forceinline__ float bf_hi(unsigned int u) {
    return __uint_as_float(u & 0xffff0000u);
}
static __device__ __forceinline__ float dpp_xor1(float x) {
    return __int_as_float(__builtin_amdgcn_mov_dpp(__float_as_int(x), 0xB1, 0xF, 0xF, true));
}
// convention-proof partner fetch (R10-R16 validated): rr0+rr1-v == v[l^K]
static __device__ __forceinline__ float xor16_get(float send) {
    auto rr = __builtin_amdgcn_permlane16_swap(__float_as_uint(send), __float_as_uint(send),
                                               false, false);
    return (__uint_as_float((unsigned)rr[0]) + __uint_as_float((unsigned)rr[1])) - send;
}
static __device__ __forceinline__ float xor32_get(float send) {
    auto rr = __builtin_amdgcn_permlane32_swap(__float_as_uint(send), __float_as_uint(send),
                                               false, false);
    return (__uint_as_float((unsigned)rr[0]) + __uint_as_float((unsigned)rr[1])) - send;
}
static __device__ __forceinline__ v4f max4(v4f a, v4f b) {
    return __builtin_elementwise_max(a, b);
}

// ---------------------------------------------------------------------------
// Setup: bf16 transition fragments (both directions, frag-major coalesced)
// and u[j] = exp(trans[j][END]).
// ---------------------------------------------------------------------------
__global__ __launch_bounds__(64) void crf_setup(const float* __restrict__ trans,
                                                s16x8* __restrict__ afws,
                                                float* __restrict__ uws) {
    const int lane = threadIdx.x;
    const int c = lane & 15, g = lane >> 4;
#pragma unroll
    for (int m = 0; m < 4; ++m)
#pragma unroll
        for (int kk = 0; kk < 2; ++kk) {
            s16x8 vf, vb;
#pragma unroll
            for (int e = 0; e < 8; ++e) {
                vf[e] = (short)f2bfu(__expf(trans[(32 * kk + 8 * g + e) * NTAGS + 16 * m + c]));
                vb[e] = (short)f2bfu(__expf(trans[(16 * m + c) * NTAGS + 32 * kk + 8 * g + e]));
            }
            afws[(0 * 8 + 2 * m + kk) * 64 + lane] = vf;
            afws[(1 * 8 + 2 * m + kk) * 64 + lane] = vb;
        }
    uws[lane] = __expf(trans[lane * NTAGS + END_TAG]);
}

// ---------------------------------------------------------------------------
// Fused fwd+bwd MFMA chain. One wave = one (segment k, 16-batch tile):
// computes BOTH r_k (fwd) and l_k (bwd), reading the segment's feats ONCE
// with COALESCED 256B row loads (lane = tag), exp'd and pair-packed to bf16
// in padded LDS (writes conflict-free; reads ~2-way aliased = free).
// Fixes R13-R16's scattered 16x64B-per-instruction E loads (~26% HBM eff).
// Step math identical to R15/R16 (absmax 0.0 there); E now bf16-rounded.
// State f32 in MFMA D layout; D->B via 4x permlane32_swap + 4x
// permlane16_swap (R14-verified). No in-loop rescale over 8 steps; one
// exact power-of-2 rescale per direction at segment output.
// ---------------------------------------------------------------------------
__global__ __launch_bounds__(64) void crf_chains(const float* __restrict__ feats,
                                                 const float* __restrict__ mask,
                                                 const int* __restrict__ tags,
                                                 const float* __restrict__ trans,
                                                 const s16x8* __restrict__ afws,
                                                 const float* __restrict__ uws,
                                                 float* __restrict__ seg,
                                                 int* __restrict__ es,
                                                 float* __restrict__ gs,
                                                 int S, int B, int nchain) {
    const int bid = (int)blockIdx.x;
    const int lane = threadIdx.x;

    if (bid >= nchain) {
        // ---- gold path score: one wave per batch ----
        const int b = bid - nchain;
        const float* fb = feats + (size_t)b * S * NTAGS;
        const float* mb = mask + (size_t)b * S;
        const int* tb = tags + (size_t)b * S;
        float acc = 0.f, msum = 0.f;
        for (int t = lane; t < S; t += 64) {
            int cur = tb[t];
            int prev = (t == 0) ? START_TAG : tb[t - 1];
            float m = mb[t];
            acc += (fb[t * NTAGS + cur] + trans[prev * NTAGS + cur]) * m;
            msum += m;
        }
#pragma unroll
        for (int sh = 32; sh >= 1; sh >>= 1) {
            acc += __shfl_xor(acc, sh);
            msum += __shfl_xor(msum, sh);
        }
        if (lane == 0) {
            int seq_end = (int)(msum + 0.5f) - 1;
            int last = (seq_end >= 0) ? tb[seq_end] : START_TAG;
            gs[b] = acc + trans[last * NTAGS + END_TAG];
        }
        return;
    }

    __shared__ unsigned int ebuf[SEGL * 16 * EP];  // 17.5 KB bf16-pair E staging

    const int ntile = B / 16;
    const int segk = bid / ntile;
    const int tile = bid - segk * ntile;
    const int b0 = tile * 16;
    const int t0 = segk * SEGL;
    const int c = lane & 15, g = lane >> 4;

    // ---- stage E: coalesced row loads (256B/inst) -> expf -> bf16 pairs ----
    for (int t = 0; t < SEGL; ++t) {
#pragma unroll
        for (int row = 0; row < 16; ++row) {
            float v = __expf(feats[((size_t)(b0 + row) * S + (t0 + t)) * NTAGS + lane]);
            float vh = dpp_xor1(v);  // partner tag (lane^1)
            if ((lane & 1) == 0)
                ebuf[(t * 16 + row) * EP + (lane >> 1)] = packbf(v, vh);
        }
    }

    // masks (tiny; 4-lane broadcast per address)
    float Mv[SEGL];
#pragma unroll
    for (int t = 0; t < SEGL; ++t) Mv[t] = mask[(size_t)(b0 + c) * S + t0 + t];

    // A fragments for both directions (8+8 coalesced b128 loads)
    s16x8 Ff[4][2], Fb[4][2];
#pragma unroll
    for (int m = 0; m < 4; ++m)
#pragma unroll
        for (int kk = 0; kk < 2; ++kk) {
            Ff[m][kk] = afws[(2 * m + kk) * 64 + lane];
            Fb[m][kk] = afws[(8 + 2 * m + kk) * 64 + lane];
        }

    // states: D0 = fwd, D1 = bwd (f32, MFMA D layout)
    v4f D0[4], D1[4];
#pragma unroll
    for (int m = 0; m < 4; ++m) D0[m] = (v4f){1.f, 1.f, 1.f, 1.f};
    if (segk == 0) {
#pragma unroll
        for (int m = 0; m < 4; ++m) D0[m] = (v4f){0.f, 0.f, 0.f, 0.f};
        if (g == 0) D0[0].y = 1.0f;  // tag 1 = START
    }
    if (segk == NSEG - 1) {
#pragma unroll
        for (int m = 0; m < 4; ++m) D1[m] = *(const v4f*)(uws + 16 * m + 4 * g);
    } else {
#pragma unroll
        for (int m = 0; m < 4; ++m) D1[m] = (v4f){1.f, 1.f, 1.f, 1.f};
    }

#define XFORM(up, bfv0, bfv1)                                                     \
    do {                                                                          \
        auto rA = __builtin_amdgcn_permlane32_swap(up[0][0], up[1][0], false, false); \
        auto rB = __builtin_amdgcn_permlane32_swap(up[0][1], up[1][1], false, false); \
        auto rC = __builtin_amdgcn_permlane32_swap(up[2][0], up[3][0], false, false); \
        auto rD = __builtin_amdgcn_permlane32_swap(up[2][1], up[3][1], false, false); \
        auto sA = __builtin_amdgcn_permlane16_swap((unsigned)rA[0], (unsigned)rA[1], false, false); \
        auto sB = __builtin_amdgcn_permlane16_swap((unsigned)rB[0], (unsigned)rB[1], false, false); \
        auto sC = __builtin_amdgcn_permlane16_swap((unsigned)rC[0], (unsigned)rC[1], false, false); \
        auto sD = __builtin_amdgcn_permlane16_swap((unsigned)rD[0], (unsigned)rD[1], false, false); \
        bfv0.d[0] = sA[0]; bfv0.d[1] = sB[0]; bfv0.d[2] = sA[1]; bfv0.d[3] = sB[1]; \
        bfv1.d[0] = sC[0]; bfv1.d[1] = sD[0]; bfv1.d[2] = sC[1]; bfv1.d[3] = sD[1]; \
    } while (0)

#pragma unroll
    for (int s = 0; s < SEGL; ++s) {
        // per-lane E dwords for fwd (t=s) and bwd (t=SEGL-1-s)
        unsigned int efw[4][2], ebw[4][2];
#pragma unroll
        for (int m = 0; m < 4; ++m)
#pragma unroll
            for (int h = 0; h < 2; ++h) {
                efw[m][h] = ebuf[(s * 16 + c) * EP + 8 * m + 2 * g + h];
                ebw[m][h] = ebuf[((SEGL - 1 - s) * 16 + c) * EP + 8 * m + 2 * g + h];
            }
        v4f Exf[4], Exb[4];
#pragma unroll
        for (int m = 0; m < 4; ++m) {
            Exf[m] = (v4f){bf_lo(efw[m][0]), bf_hi(efw[m][0]),
                           bf_lo(efw[m][1]), bf_hi(efw[m][1])};
            Exb[m] = (v4f){bf_lo(ebw[m][0]), bf_hi(ebw[m][0]),
                           bf_lo(ebw[m][1]), bf_hi(ebw[m][1])};
        }

        // ---- fwd step: Dm = (A^T D0) * E[s], select Mv[s] ----
        {
            unsigned int up[4][2];
#pragma unroll
            for (int n = 0; n < 4; ++n) {
                up[n][0] = packbf(D0[n].x, D0[n].y);
                up[n][1] = packbf(D0[n].z, D0[n].w);
            }
            union { unsigned int d[4]; s16x8 v; } bf0, bf1;
            XFORM(up, bf0, bf1);
            v4f Dm[4];
#pragma unroll
            for (int m = 0; m < 4; ++m) {
                v4f z = (v4f){0.f, 0.f, 0.f, 0.f};
                Dm[m] = __builtin_amdgcn_mfma_f32_16x16x32_bf16(Ff[m][0], bf0.v, z, 0, 0, 0);
                Dm[m] = __builtin_amdgcn_mfma_f32_16x16x32_bf16(Ff[m][1], bf1.v, Dm[m], 0, 0, 0);
                Dm[m] = Dm[m] * Exf[m];
            }
            bool act = (Mv[s] != 0.0f);
#pragma unroll
            for (int m = 0; m < 4; ++m) D0[m] = act ? Dm[m] : D0[m];
        }

        // ---- bwd step: Dm = A (E[SEGL-1-s] * D1), select Mv[SEGL-1-s] ----
        {
            unsigned int up[4][2];
#pragma unroll
            for (int n = 0; n < 4; ++n) {
                v4f sv = D1[n] * Exb[n];
                up[n][0] = packbf(sv.x, sv.y);
                up[n][1] = packbf(sv.z, sv.w);
            }
            union { unsigned int d[4]; s16x8 v; } bf0, bf1;
            XFORM(up, bf0, bf1);
            v4f Dm[4];
#pragma unroll
            for (int m = 0; m < 4; ++m) {
                v4f z = (v4f){0.f, 0.f, 0.f, 0.f};
                Dm[m] = __builtin_amdgcn_mfma_f32_16x16x32_bf16(Fb[m][0], bf0.v, z, 0, 0, 0);
                Dm[m] = __builtin_amdgcn_mfma_f32_16x16x32_bf16(Fb[m][1], bf1.v, Dm[m], 0, 0, 0);
            }
            bool act = (Mv[SEGL - 1 - s] != 0.0f);
#pragma unroll
            for (int m = 0; m < 4; ++m) D1[m] = act ? Dm[m] : D1[m];
        }
    }
#undef XFORM

    // ---- epilogue: exact power-of-2 rescale + write (guarded per type) ----
    if (segk < NSEG - 1) {  // fwd type = segk (0..62)
        int ex0 = 0;
        v4f mm = max4(max4(D0[0], D0[1]), max4(D0[2], D0[3]));
        float mx = fmaxf(fmaxf(mm.x, mm.y), fmaxf(mm.z, mm.w));
        mx = fmaxf(mx, xor16_get(mx));
        mx = fmaxf(mx, xor32_get(mx));
        int ef = (__float_as_int(mx) >> 23) & 0xFF;
        if (ef != 0) {
            ex0 = ef - 127;
#pragma unroll
            for (int m = 0; m < 4; ++m) {
                D0[m].x = ldexpf(D0[m].x, -ex0); D0[m].y = ldexpf(D0[m].y, -ex0);
                D0[m].z = ldexpf(D0[m].z, -ex0); D0[m].w = ldexpf(D0[m].w, -ex0);
            }
        }
        float* oc = seg + ((size_t)segk * B + b0 + c) * NTAGS;
#pragma unroll
        for (int m = 0; m < 4; ++m) *(v4f*)(oc + 16 * m + 4 * g) = D0[m];
        if (g == 0) es[(size_t)segk * B + b0 + c] = ex0;
    }
    if (segk > 0) {  // bwd type = 62 + segk (63..125)
        int ex1 = 0;
        v4f mm = max4(max4(D1[0], D1[1]), max4(D1[2], D1[3]));
        float mx = fmaxf(fmaxf(mm.x, mm.y), fmaxf(mm.z, mm.w));
        mx = fmaxf(mx, xor16_get(mx));
        mx = fmaxf(mx, xor32_get(mx));
        int ef = (__float_as_int(mx) >> 23) & 0xFF;
        if (ef != 0) {
            ex1 = ef - 127;
#pragma unroll
            for (int m = 0; m < 4; ++m) {
                D1[m].x = ldexpf(D1[m].x, -ex1); D1[m].y = ldexpf(D1[m].y, -ex1);
                D1[m].z = ldexpf(D1[m].z, -ex1); D1[m].w = ldexpf(D1[m].w, -ex1);
            }
        }
        const int type = 62 + segk;
        float* oc = seg + ((size_t)type * B + b0 + c) * NTAGS;
#pragma unroll
        for (int m = 0; m < 4; ++m) *(v4f*)(oc + 16 * m + 4 * g) = D1[m];
        if (g == 0) es[(size_t)type * B + b0 + c] = ex1;
    }
}

// ---------------------------------------------------------------------------
// Lane-parallel bridging (R15-verified): lane j<63 owns bridge g=j+1:
//   contrib = ln(l_g . r_{g-1}) + ln2*es_fwd[g-1] - (g<=62 ? ln(sum l_g) : 0)
// lane 63: ln2*es_bwd[63]. Probe-l exponents cancel.
// ---------------------------------------------------------------------------
__global__ __launch_bounds__(512) void crf_finish(const float* __restrict__ seg,
                                                  const int* __restrict__ es,
                                                  const float* __restrict__ gs,
                                                  float* __restrict__ scores, int B) {
    const int tid = threadIdx.x;
    const int wave = tid >> 6, lane = tid & 63;
    const int b = blockIdx.x * 8 + wave;
    if (b >= B) return;

    float contrib = 0.f;
    if (lane < 63) {
        const int g = lane + 1;  // bridge 1..63
        const float* rv = seg + ((size_t)(g - 1) * B + b) * NTAGS;
        const float* lv = seg + ((size_t)(62 + g) * B + b) * NTAGS;
        v4f dacc = (v4f){0.f, 0.f, 0.f, 0.f};
        v4f sacc = dacc;
#pragma unroll
        for (int i = 0; i < 16; ++i) {
            v4f rr = *(const v4f*)(rv + 4 * i);
            v4f ll = *(const v4f*)(lv + 4 * i);
            dacc = __builtin_elementwise_fma(ll, rr, dacc);
            sacc = sacc + ll;
        }
        float dot = (dacc.x + dacc.y) + (dacc.z + dacc.w);
        float sl = (sacc.x + sacc.y) + (sacc.z + sacc.w);
        contrib = __logf(dot) + (float)es[(size_t)(g - 1) * B + b] * LN2F;
        if (g <= 62) contrib -= __logf(sl);
    } else {
        contrib = (float)es[(size_t)125 * B + b] * LN2F;
    }
#pragma unroll
    for (int sh = 32; sh >= 1; sh >>= 1) contrib += __shfl_xor(contrib, sh);
    if (lane == 0) scores[b] = contrib - gs[b];
}

__global__ __launch_bounds__(1024) void crf_mean(const float* __restrict__ scores,
                                                 float* __restrict__ out, int B) {
    const int tid = threadIdx.x;
    float a = 0.f;
    for (int i = tid; i < B; i += 1024) a += scores[i];
#pragma unroll
    for (int sh = 32; sh >= 1; sh >>= 1) a += __shfl_xor(a, sh);
    __shared__ float buf[16];
    if ((tid & 63) == 0) buf[tid >> 6] = a;
    __syncthreads();
    if (tid == 0) {
        float s = 0.f;
#pragma unroll
        for (int i = 0; i < 16; ++i) s += buf[i];
        out[0] = s / (float)B;
    }
}

extern "C" void kernel_launch(void* const* d_in, const int* in_sizes, int n_in,
                              void* d_out, int out_size, void* d_ws, size_t ws_size,
                              hipStream_t stream) {
    const float* feats = (const float*)d_in[0];
    const float* mask  = (const float*)d_in[1];
    const int*   tags  = (const int*)d_in[2];
    const float* trans = (const float*)d_in[3];
    float* out = (float*)d_out;

    const int S = 512;              // reference shape
    const int B = in_sizes[1] / S;  // mask is (B,S)
    const int nchain = NSEG * (B / 16);  // fused fwd+bwd per (seg, tile)

    float* afws = (float*)d_ws;                        // 4096 floats (16 KB)
    float* uws = afws + 4096;                          // 64
    float* seg = uws + 64;                             // [126][B][64]
    int* es = (int*)(seg + (size_t)126 * B * NTAGS);   // [126][B]
    float* gs = (float*)(es + 126 * B);                // [B]
    float* scores = gs + B;                            // [B]

    crf_setup<<<1, 64, 0, stream>>>(trans, (s16x8*)afws, uws);
    crf_chains<<<nchain + B, 64, 0, stream>>>(feats, mask, tags, trans,
                                              (const s16x8*)afws, uws,
                                              seg, es, gs, S, B, nchain);
    crf_finish<<<(B + 7) / 8, 512, 0, stream>>>(seg, es, gs, scores, B);
    crf_mean<<<1, 1024, 0, stream>>>(scores, out, B);
}

// Round 18
// 53.819 us; speedup vs baseline: 1.4062x; 1.4062x over previous
//
#include <hip/hip_runtime.h>
#include <hip/hip_bf16.h>

#define NTAGS 64
#define START_TAG 1
#define END_TAG 63
#define LN2F 0.69314718055994530942f
#define NSEG 64
#define SEGL 8
#define EPD 1088  // padded dwords per staged step: 16 batches * 68 (64+4 pad)

typedef float v4f __attribute__((ext_vector_type(4)));
typedef short s16x8 __attribute__((ext_vector_type(8)));

static __device__ __forceinline__ unsigned short f2bfu(float x) {
    union { __hip_bfloat16 h; unsigned short s; } u;
    u.h = __float2bfloat16(x);
    return u.s;
}
static __device__ __forceinline__ unsigned int packbf(float lo, float hi) {
    return (unsigned int)f2bfu(lo) | ((unsigned int)f2bfu(hi) << 16);
}
// convention-proof partner fetch (R10-R17 validated): rr0+rr1-v == v[l^K]
static __device__ __forceinline__ float xor16_get(float send) {
    auto rr = __builtin_amdgcn_permlane16_swap(__float_as_uint(send), __float_as_uint(send),
                                               false, false);
    return (__uint_as_float((unsigned)rr[0]) + __uint_as_float((unsigned)rr[1])) - send;
}
static __device__ __forceinline__ float xor32_get(float send) {
    auto rr = __builtin_amdgcn_permlane32_swap(__float_as_uint(send), __float_as_uint(send),
                                               false, false);
    return (__uint_as_float((unsigned)rr[0]) + __uint_as_float((unsigned)rr[1])) - send;
}
static __device__ __forceinline__ v4f max4(v4f a, v4f b) {
    return __builtin_elementwise_max(a, b);
}
// async global->LDS, 4B per lane; LDS dest is wave-uniform base (+lane*4 by HW)
static __device__ __forceinline__ void gl_lds_dword(const float* g, float* lds_base) {
    __builtin_amdgcn_global_load_lds(
        (const __attribute__((address_space(1))) void*)g,
        (__attribute__((address_space(3))) void*)lds_base, 4, 0, 0);
}

// ---------------------------------------------------------------------------
// Setup: bf16 transition fragments (both directions, frag-major coalesced)
// and u[j] = exp(trans[j][END]).
// ---------------------------------------------------------------------------
__global__ __launch_bounds__(64) void crf_setup(const float* __restrict__ trans,
                                                s16x8* __restrict__ afws,
                                                float* __restrict__ uws) {
    const int lane = threadIdx.x;
    const int c = lane & 15, g = lane >> 4;
#pragma unroll
    for (int m = 0; m < 4; ++m)
#pragma unroll
        for (int kk = 0; kk < 2; ++kk) {
            s16x8 vf, vb;
#pragma unroll
            for (int e = 0; e < 8; ++e) {
                vf[e] = (short)f2bfu(__expf(trans[(32 * kk + 8 * g + e) * NTAGS + 16 * m + c]));
                vb[e] = (short)f2bfu(__expf(trans[(16 * m + c) * NTAGS + 32 * kk + 8 * g + e]));
            }
            afws[(0 * 8 + 2 * m + kk) * 64 + lane] = vf;
            afws[(1 * 8 + 2 * m + kk) * 64 + lane] = vb;
        }
    uws[lane] = __expf(trans[lane * NTAGS + END_TAG]);
}

// ---------------------------------------------------------------------------
// Fused fwd+bwd MFMA chain; one wave = one (segment, 16-batch tile).
// E staged whole-segment by 136 fire-and-forget global_load_lds dwords into
// a stride-68-padded f32 LDS image (17 instr/step; 1088=16*68; per-lane
// pre-swizzled sources, pads clamped), single vmcnt(0), then 8 fused steps:
// padded ds_read_b128 E reads (bank-uniform), in-loop expf, R16's verified
// MFMA step (state f32 in D layout; D->B via 4x permlane32_swap +
// 4x permlane16_swap). One exact power-of-2 rescale per direction at output.
// ---------------------------------------------------------------------------
__global__ __launch_bounds__(64) void crf_chains(const float* __restrict__ feats,
                                                 const float* __restrict__ mask,
                                                 const int* __restrict__ tags,
                                                 const float* __restrict__ trans,
                                                 const s16x8* __restrict__ afws,
                                                 const float* __restrict__ uws,
                                                 float* __restrict__ seg,
                                                 int* __restrict__ es,
                                                 float* __restrict__ gs,
                                                 int S, int B, int nchain) {
    const int bid = (int)blockIdx.x;
    const int lane = threadIdx.x;

    if (bid >= nchain) {
        // ---- gold path score: one wave per batch ----
        const int b = bid - nchain;
        const float* fb = feats + (size_t)b * S * NTAGS;
        const float* mb = mask + (size_t)b * S;
        const int* tb = tags + (size_t)b * S;
        float acc = 0.f, msum = 0.f;
        for (int t = lane; t < S; t += 64) {
            int cur = tb[t];
            int prev = (t == 0) ? START_TAG : tb[t - 1];
            float m = mb[t];
            acc += (fb[t * NTAGS + cur] + trans[prev * NTAGS + cur]) * m;
            msum += m;
        }
#pragma unroll
        for (int sh = 32; sh >= 1; sh >>= 1) {
            acc += __shfl_xor(acc, sh);
            msum += __shfl_xor(msum, sh);
        }
        if (lane == 0) {
            int seq_end = (int)(msum + 0.5f) - 1;
            int last = (seq_end >= 0) ? tb[seq_end] : START_TAG;
            gs[b] = acc + trans[last * NTAGS + END_TAG];
        }
        return;
    }

    __shared__ __align__(16) float ebuf[SEGL * EPD];  // 34816 B

    const int ntile = B / 16;
    const int segk = bid / ntile;
    const int tile = bid - segk * ntile;
    const int b0 = tile * 16;
    const int t0 = segk * SEGL;
    const int c = lane & 15, g = lane >> 4;

    // A fragments for both directions (16 coalesced b128 loads)
    s16x8 Ff[4][2], Fb[4][2];
#pragma unroll
    for (int m = 0; m < 4; ++m)
#pragma unroll
        for (int kk = 0; kk < 2; ++kk) {
            Ff[m][kk] = afws[(2 * m + kk) * 64 + lane];
            Fb[m][kk] = afws[(8 + 2 * m + kk) * 64 + lane];
        }

    // per-lane swizzled source bases: padded idx k*64+lane -> (batch, tag)
    const float* Aks[17];
#pragma unroll
    for (int k = 0; k < 17; ++k) {
        int idx = k * 64 + lane;
        int cc = idx / 68;
        int rr = idx - cc * 68;
        int tg = (rr > 63) ? 63 : rr;  // pad dwords: harmless duplicate source
        Aks[k] = feats + ((size_t)(b0 + cc) * S) * NTAGS + tg;
    }
    // fire-and-forget staging: 136 global_load_lds dwords, linear LDS dest
#pragma unroll
    for (int t = 0; t < SEGL; ++t)
#pragma unroll
        for (int k = 0; k < 17; ++k)
            gl_lds_dword(Aks[k] + (size_t)(t0 + t) * NTAGS, &ebuf[t * EPD + k * 64]);

    // masks for this tile (lane c's batch), both directions use same 8
    float Mv[SEGL];
#pragma unroll
    for (int t = 0; t < SEGL; ++t) Mv[t] = mask[(size_t)(b0 + c) * S + t0 + t];

    // states: D0 = fwd, D1 = bwd (f32, MFMA D layout)
    v4f D0[4], D1[4];
#pragma unroll
    for (int m = 0; m < 4; ++m) D0[m] = (v4f){1.f, 1.f, 1.f, 1.f};
    if (segk == 0) {
#pragma unroll
        for (int m = 0; m < 4; ++m) D0[m] = (v4f){0.f, 0.f, 0.f, 0.f};
        if (g == 0) D0[0].y = 1.0f;  // tag 1 = START
    }
    if (segk == NSEG - 1) {
#pragma unroll
        for (int m = 0; m < 4; ++m) D1[m] = *(const v4f*)(uws + 16 * m + 4 * g);
    } else {
#pragma unroll
        for (int m = 0; m < 4; ++m) D1[m] = (v4f){1.f, 1.f, 1.f, 1.f};
    }

    asm volatile("s_waitcnt vmcnt(0)" ::: "memory");  // staging complete (1-wave block)

#define XFORM(up, bfv0, bfv1)                                                     \
    do {                                                                          \
        auto rA = __builtin_amdgcn_permlane32_swap(up[0][0], up[1][0], false, false); \
        auto rB = __builtin_amdgcn_permlane32_swap(up[0][1], up[1][1], false, false); \
        auto rC = __builtin_amdgcn_permlane32_swap(up[2][0], up[3][0], false, false); \
        auto rD = __builtin_amdgcn_permlane32_swap(up[2][1], up[3][1], false, false); \
        auto sA = __builtin_amdgcn_permlane16_swap((unsigned)rA[0], (unsigned)rA[1], false, false); \
        auto sB = __builtin_amdgcn_permlane16_swap((unsigned)rB[0], (unsigned)rB[1], false, false); \
        auto sC = __builtin_amdgcn_permlane16_swap((unsigned)rC[0], (unsigned)rC[1], false, false); \
        auto sD = __builtin_amdgcn_permlane16_swap((unsigned)rD[0], (unsigned)rD[1], false, false); \
        bfv0.d[0] = sA[0]; bfv0.d[1] = sB[0]; bfv0.d[2] = sA[1]; bfv0.d[3] = sB[1]; \
        bfv1.d[0] = sC[0]; bfv1.d[1] = sD[0]; bfv1.d[2] = sC[1]; bfv1.d[3] = sD[1]; \
    } while (0)

#pragma unroll
    for (int s = 0; s < SEGL; ++s) {
        const float* Ef = &ebuf[s * EPD + c * 68];
        const float* Eb = &ebuf[(SEGL - 1 - s) * EPD + c * 68];
        v4f Exf[4], Exb[4];
#pragma unroll
        for (int n = 0; n < 4; ++n) {
            v4f rf = *(const v4f*)(Ef + 16 * n + 4 * g);
            v4f rb = *(const v4f*)(Eb + 16 * n + 4 * g);
            Exf[n] = (v4f){__expf(rf.x), __expf(rf.y), __expf(rf.z), __expf(rf.w)};
            Exb[n] = (v4f){__expf(rb.x), __expf(rb.y), __expf(rb.z), __expf(rb.w)};
        }

        // ---- fwd step: D0 = (A^T D0) * E[s] (masked) ----
        {
            unsigned int up[4][2];
#pragma unroll
            for (int n = 0; n < 4; ++n) {
                up[n][0] = packbf(D0[n].x, D0[n].y);
                up[n][1] = packbf(D0[n].z, D0[n].w);
            }
            union { unsigned int d[4]; s16x8 v; } bf0, bf1;
            XFORM(up, bf0, bf1);
            v4f Dm[4];
#pragma unroll
            for (int m = 0; m < 4; ++m) {
                v4f z = (v4f){0.f, 0.f, 0.f, 0.f};
                Dm[m] = __builtin_amdgcn_mfma_f32_16x16x32_bf16(Ff[m][0], bf0.v, z, 0, 0, 0);
                Dm[m] = __builtin_amdgcn_mfma_f32_16x16x32_bf16(Ff[m][1], bf1.v, Dm[m], 0, 0, 0);
                Dm[m] = Dm[m] * Exf[m];
            }
            bool act = (Mv[s] != 0.0f);
#pragma unroll
            for (int m = 0; m < 4; ++m) D0[m] = act ? Dm[m] : D0[m];
        }

        // ---- bwd step: D1 = A (E[7-s] * D1) (masked) ----
        {
            unsigned int up[4][2];
#pragma unroll
            for (int n = 0; n < 4; ++n) {
                v4f sv = D1[n] * Exb[n];
                up[n][0] = packbf(sv.x, sv.y);
                up[n][1] = packbf(sv.z, sv.w);
            }
            union { unsigned int d[4]; s16x8 v; } bf0, bf1;
            XFORM(up, bf0, bf1);
            v4f Dm[4];
#pragma unroll
            for (int m = 0; m < 4; ++m) {
                v4f z = (v4f){0.f, 0.f, 0.f, 0.f};
                Dm[m] = __builtin_amdgcn_mfma_f32_16x16x32_bf16(Fb[m][0], bf0.v, z, 0, 0, 0);
                Dm[m] = __builtin_amdgcn_mfma_f32_16x16x32_bf16(Fb[m][1], bf1.v, Dm[m], 0, 0, 0);
            }
            bool act = (Mv[SEGL - 1 - s] != 0.0f);
#pragma unroll
            for (int m = 0; m < 4; ++m) D1[m] = act ? Dm[m] : D1[m];
        }
    }
#undef XFORM

    // ---- epilogue: exact power-of-2 rescale + write (guarded per type) ----
    if (segk < NSEG - 1) {  // fwd type = segk (0..62)
        int ex0 = 0;
        v4f mm = max4(max4(D0[0], D0[1]), max4(D0[2], D0[3]));
        float mx = fmaxf(fmaxf(mm.x, mm.y), fmaxf(mm.z, mm.w));
        mx = fmaxf(mx, xor16_get(mx));
        mx = fmaxf(mx, xor32_get(mx));
        int ef = (__float_as_int(mx) >> 23) & 0xFF;
        if (ef != 0) {
            ex0 = ef - 127;
#pragma unroll
            for (int m = 0; m < 4; ++m) {
                D0[m].x = ldexpf(D0[m].x, -ex0); D0[m].y = ldexpf(D0[m].y, -ex0);
                D0[m].z = ldexpf(D0[m].z, -ex0); D0[m].w = ldexpf(D0[m].w, -ex0);
            }
        }
        float* oc = seg + ((size_t)segk * B + b0 + c) * NTAGS;
#pragma unroll
        for (int m = 0; m < 4; ++m) *(v4f*)(oc + 16 * m + 4 * g) = D0[m];
        if (g == 0) es[(size_t)segk * B + b0 + c] = ex0;
    }
    if (segk > 0) {  // bwd type = 62 + segk (63..125)
        int ex1 = 0;
        v4f mm = max4(max4(D1[0], D1[1]), max4(D1[2], D1[3]));
        float mx = fmaxf(fmaxf(mm.x, mm.y), fmaxf(mm.z, mm.w));
        mx = fmaxf(mx, xor16_get(mx));
        mx = fmaxf(mx, xor32_get(mx));
        int ef = (__float_as_int(mx) >> 23) & 0xFF;
        if (ef != 0) {
            ex1 = ef - 127;
#pragma unroll
            for (int m = 0; m < 4; ++m) {
                D1[m].x = ldexpf(D1[m].x, -ex1); D1[m].y = ldexpf(D1[m].y, -ex1);
                D1[m].z = ldexpf(D1[m].z, -ex1); D1[m].w = ldexpf(D1[m].w, -ex1);
            }
        }
        const int type = 62 + segk;
        float* oc = seg + ((size_t)type * B + b0 + c) * NTAGS;
#pragma unroll
        for (int m = 0; m < 4; ++m) *(v4f*)(oc + 16 * m + 4 * g) = D1[m];
        if (g == 0) es[(size_t)type * B + b0 + c] = ex1;
    }
}

// ---------------------------------------------------------------------------
// Lane-parallel bridging (R15-verified): lane j<63 owns bridge g=j+1:
//   contrib = ln(l_g . r_{g-1}) + ln2*es_fwd[g-1] - (g<=62 ? ln(sum l_g) : 0)
// lane 63: ln2*es_bwd[63]. Probe-l exponents cancel.
// ---------------------------------------------------------------------------
__global__ __launch_bounds__(512) void crf_finish(const float* __restrict__ seg,
                                                  const int* __restrict__ es,
                                                  const float* __restrict__ gs,
                                                  float* __restrict__ scores, int B) {
    const int tid = threadIdx.x;
    const int wave = tid >> 6, lane = tid & 63;
    const int b = blockIdx.x * 8 + wave;
    if (b >= B) return;

    float contrib = 0.f;
    if (lane < 63) {
        const int g = lane + 1;  // bridge 1..63
        const float* rv = seg + ((size_t)(g - 1) * B + b) * NTAGS;
        const float* lv = seg + ((size_t)(62 + g) * B + b) * NTAGS;
        v4f dacc = (v4f){0.f, 0.f, 0.f, 0.f};
        v4f sacc = dacc;
#pragma unroll
        for (int i = 0; i < 16; ++i) {
            v4f rr = *(const v4f*)(rv + 4 * i);
            v4f ll = *(const v4f*)(lv + 4 * i);
            dacc = __builtin_elementwise_fma(ll, rr, dacc);
            sacc = sacc + ll;
        }
        float dot = (dacc.x + dacc.y) + (dacc.z + dacc.w);
        float sl = (sacc.x + sacc.y) + (sacc.z + sacc.w);
        contrib = __logf(dot) + (float)es[(size_t)(g - 1) * B + b] * LN2F;
        if (g <= 62) contrib -= __logf(sl);
    } else {
        contrib = (float)es[(size_t)125 * B + b] * LN2F;
    }
#pragma unroll
    for (int sh = 32; sh >= 1; sh >>= 1) contrib += __shfl_xor(contrib, sh);
    if (lane == 0) scores[b] = contrib - gs[b];
}

__global__ __launch_bounds__(1024) void crf_mean(const float* __restrict__ scores,
                                                 float* __restrict__ out, int B) {
    const int tid = threadIdx.x;
    float a = 0.f;
    for (int i = tid; i < B; i += 1024) a += scores[i];
#pragma unroll
    for (int sh = 32; sh >= 1; sh >>= 1) a += __shfl_xor(a, sh);
    __shared__ float buf[16];
    if ((tid & 63) == 0) buf[tid >> 6] = a;
    __syncthreads();
    if (tid == 0) {
        float s = 0.f;
#pragma unroll
        for (int i = 0; i < 16; ++i) s += buf[i];
        out[0] = s / (float)B;
    }
}

extern "C" void kernel_launch(void* const* d_in, const int* in_sizes, int n_in,
                              void* d_out, int out_size, void* d_ws, size_t ws_size,
                              hipStream_t stream) {
    const float* feats = (const float*)d_in[0];
    const float* mask  = (const float*)d_in[1];
    const int*   tags  = (const int*)d_in[2];
    const float* trans = (const float*)d_in[3];
    float* out = (float*)d_out;

    const int S = 512;              // reference shape
    const int B = in_sizes[1] / S;  // mask is (B,S)
    const int nchain = NSEG * (B / 16);  // fused fwd+bwd per (seg, tile)

    float* afws = (float*)d_ws;                        // 4096 floats (16 KB)
    float* uws = afws + 4096;                          // 64
    float* seg = uws + 64;                             // [126][B][64]
    int* es = (int*)(seg + (size_t)126 * B * NTAGS);   // [126][B]
    float* gs = (float*)(es + 126 * B);                // [B]
    float* scores = gs + B;                            // [B]

    crf_setup<<<1, 64, 0, stream>>>(trans, (s16x8*)afws, uws);
    crf_chains<<<nchain + B, 64, 0, stream>>>(feats, mask, tags, trans,
                                              (const s16x8*)afws, uws,
                                              seg, es, gs, S, B, nchain);
    crf_finish<<<(B + 7) / 8, 512, 0, stream>>>(seg, es, gs, scores, B);
    crf_mean<<<1, 1024, 0, stream>>>(scores, out, B);
}